// Round 11
// baseline (326.489 us; speedup 1.0000x reference)
//
#include <hip/hip_runtime.h>

// SparseMoE: B=2,S=2048 -> N=4096 tokens, D=1024, HIDDEN=2816, 8 experts, top-2, cap=1024
// Round 11: proven r6 GEMM cores + conversion hidden in existing dispatches:
//  - cvt(w1,w3) merged into gather dispatch (both branches register-light -> no
//    joint-regalloc starvation, unlike the r9/r10 router merge)
//  - cvt(w2) dripped into gemm12's epilogue (WELEM = 704 blocks x 32768 floats exactly);
//    rides under the K-loop's idle HBM (~1.8 of 6.3 TB/s)
//  - router standalone again (unbounded regs; r9/r10 starvation tax removed)

#define D_MODEL 1024
#define HIDDEN 2816
#define N_TOK 4096
#define CAP 1024

typedef __attribute__((ext_vector_type(8))) short short8;
typedef __attribute__((ext_vector_type(4))) float f32x4;

__device__ __forceinline__ unsigned short f2bf(float f) {
  unsigned int u = __float_as_uint(f);
  u += 0x7fffu + ((u >> 16) & 1u);   // RNE
  return (unsigned short)(u >> 16);
}
__device__ __forceinline__ float bf2f(unsigned short h) {
  return __uint_as_float(((unsigned int)h) << 16);
}

template <int Ncnt> __device__ __forceinline__ void waitv() {
  if constexpr (Ncnt == 8)      asm volatile("s_waitcnt vmcnt(8)" ::: "memory");
  else if constexpr (Ncnt == 6) asm volatile("s_waitcnt vmcnt(6)" ::: "memory");
  else                          asm volatile("s_waitcnt vmcnt(0)" ::: "memory");
}

// ---------------- router: logits, noisy top-2, gates ----------------
__global__ void router_kernel(const float* __restrict__ x, const float* __restrict__ noise,
                              const float* __restrict__ rw, const float* __restrict__ rb,
                              const float* __restrict__ nw, const float* __restrict__ nb,
                              int* __restrict__ topi, float* __restrict__ gall,
                              int* __restrict__ slot) {
  int wid = threadIdx.x >> 6;
  int lane = threadIdx.x & 63;
  int t = blockIdx.x * 4 + wid;
  if (t >= N_TOK) return;
  const float* xr = x + (size_t)t * D_MODEL;
  double accL[8] = {0,0,0,0,0,0,0,0};
  double accN[8] = {0,0,0,0,0,0,0,0};
  for (int i = 0; i < 4; ++i) {
    int kb = (i * 64 + lane) * 4;
    float4 xv = *(const float4*)(xr + kb);
#pragma unroll
    for (int e = 0; e < 8; ++e) {
      float4 wv = *(const float4*)(rw + e * D_MODEL + kb);
      accL[e] += (double)xv.x * wv.x + (double)xv.y * wv.y + (double)xv.z * wv.z + (double)xv.w * wv.w;
      float4 nv = *(const float4*)(nw + e * D_MODEL + kb);
      accN[e] += (double)xv.x * nv.x + (double)xv.y * nv.y + (double)xv.z * nv.z + (double)xv.w * nv.w;
    }
  }
#pragma unroll
  for (int e = 0; e < 8; ++e) {
    for (int s = 32; s > 0; s >>= 1) {
      accL[e] += __shfl_xor(accL[e], s);
      accN[e] += __shfl_xor(accN[e], s);
    }
  }
  if (lane == 0) {
    double noisy[8];
#pragma unroll
    for (int e = 0; e < 8; ++e) {
      double lg = accL[e] + (double)rb[e];
      double nl = accN[e] + (double)nb[e];
      double sp = (nl > 0.0 ? nl : 0.0) + log1p(exp(-fabs(nl)));  // softplus, stable
      noisy[e] = lg + (double)noise[t * 8 + e] * sp;
    }
    int i0 = 0;
    for (int e = 1; e < 8; ++e) if (noisy[e] > noisy[i0]) i0 = e;
    int i1 = -1;
    for (int e = 0; e < 8; ++e) { if (e == i0) continue; if (i1 < 0 || noisy[e] > noisy[i1]) i1 = e; }
    double g0 = 1.0 / (1.0 + exp(noisy[i1] - noisy[i0]));
    topi[t * 2] = i0; topi[t * 2 + 1] = i1;
    gall[t * 2] = (float)g0; gall[t * 2 + 1] = (float)(1.0 - g0);
    slot[t * 2] = -1; slot[t * 2 + 1] = -1;
  }
}

// ---------------- per-expert capacity scan (token-index order) ----------------
__global__ void scan_kernel(const int* __restrict__ topi,
                            int* __restrict__ slot, int* __restrict__ tok_list) {
  int e = blockIdx.x;
  int tid = threadIdx.x;
  int lane = tid & 63, wid = tid >> 6;
  __shared__ int wsum[16];
  __shared__ int base_s;
  tok_list[e * CAP + tid] = -1;
  if (tid == 0) base_s = 0;
  __syncthreads();
  for (int chunk = 0; chunk < N_TOK / 1024; ++chunk) {
    int t = chunk * 1024 + tid;
    int i0 = topi[t * 2], i1 = topi[t * 2 + 1];
    bool m = (i0 == e) || (i1 == e);
    unsigned long long mask = __ballot(m);
    int excl = __popcll(mask & ((1ull << lane) - 1ull));
    if (lane == 0) wsum[wid] = __popcll(mask);
    __syncthreads();
    int base = base_s;
    int woff = 0;
    for (int w = 0; w < wid; ++w) woff += wsum[w];
    int pos = base + woff + excl;
    if (m && pos < CAP) {
      tok_list[e * CAP + pos] = t;
      if (i0 == e) slot[t * 2] = pos; else slot[t * 2 + 1] = pos;
    }
    __syncthreads();
    if (tid == 0) {
      int s = 0;
      for (int w = 0; w < 16; ++w) s += wsum[w];
      base_s = base + s;
    }
    __syncthreads();
  }
}

// ------- gather (blocks 0..8191) + cvt w1/w3 (blocks 8192..) in one dispatch -------
// Both branches are register-light streaming code: no joint-regalloc starvation.
__global__ void gather_cvt_kernel(const float* __restrict__ x, const int* __restrict__ tok_list,
                                  unsigned short* __restrict__ xb,
                                  const float* __restrict__ w1, const float* __restrict__ w3,
                                  unsigned short* __restrict__ wb1,
                                  unsigned short* __restrict__ wb3) {
  if (blockIdx.x < 8192) {
    int row = blockIdx.x;
    int tok = tok_list[row];
    unsigned short* dst = xb + (size_t)row * D_MODEL + threadIdx.x * 4;
    if (tok < 0) {
      *(ushort4*)dst = make_ushort4(0, 0, 0, 0);
    } else {
      float4 v = *(const float4*)(x + (size_t)tok * D_MODEL + threadIdx.x * 4);
      *(ushort4*)dst = make_ushort4(f2bf(v.x), f2bf(v.y), f2bf(v.z), f2bf(v.w));
    }
    return;
  }
  constexpr size_t Q4 = (size_t)8 * HIDDEN * D_MODEL / 4;   // float4s per weight array
  size_t i = (size_t)(blockIdx.x - 8192) * 256 + threadIdx.x;
  const float* src = (i < Q4) ? w1 : w3;
  unsigned short* dst = (i < Q4) ? wb1 : wb3;
  size_t off = (i < Q4) ? i : i - Q4;
  float4 v = *(const float4*)(src + off * 4);
  *(ushort4*)(dst + off * 4) = make_ushort4(f2bf(v.x), f2bf(v.y), f2bf(v.z), f2bf(v.w));
}

// ============ grouped GEMM core (gload_lds + src-swizzle + counted vmcnt) ============
// BM=256, 8 waves (2M x 4N), NW B-panels of 128 cols each, optional split-K.
// MODE 1 (FUSE): panels = w1,w3 at same cols; epilogue silu(acc0)*acc1 -> bf16 h,
//                then drips this block's 32768-float slice of w2 -> wb2 (f32->bf16).
// MODE 2 (PART): panels = adjacent 128-col halves of w2 (BNCOL=256), split-K SK=2;
//                epilogue stores ungated f32 partials (no atomics).
template <int NOUT, int K, int NW, int MODE>
__global__ __launch_bounds__(512, 1)
void gemm_moe(const unsigned short* __restrict__ Ab, const unsigned short* __restrict__ B0,
              const unsigned short* __restrict__ B1, void* __restrict__ OUT,
              const float* __restrict__ W2src, unsigned short* __restrict__ WB2dst) {
  constexpr int ABYTES = 32768;
  constexpr int BUFSZ = ABYTES + NW * 16384;
  constexpr int KT = K / 64;
  constexpr int SK = (MODE == 2) ? 2 : 1;
  constexpr int KTS = KT / SK;
  constexpr int BNCOL = (MODE == 2 && NW == 2) ? 256 : 128;
  constexpr int NBN = NOUT / BNCOL;
  constexpr int NWG = 8 * 4 * NBN * SK;
  constexpr int CPW = (32 + NW * 16) / 8;   // gload_lds per thread per stage: 8 or 6

  __shared__ char smem[2 * BUFSZ];

  // bijective XCD swizzle + decode (NWG % 8 == 0)
  int lid = blockIdx.x;
  int swz = (lid & 7) * (NWG / 8) + (lid >> 3);
  constexpr int PERE = 4 * NBN * SK;
  int e = swz / PERE;
  int r = swz - e * PERE;
  int bm = r / (NBN * SK);
  int r2 = r - bm * (NBN * SK);
  int bn = r2 / SK;
  int sk = r2 - bn * SK;
  int kt0 = sk * KTS;

  const unsigned short* A = Ab + (size_t)e * CAP * K;
  int tid = threadIdx.x, lane = tid & 63, wid = tid >> 6;
  int wr = wid >> 2, wc = wid & 3;
  int lane15 = lane & 15, lhi = lane >> 4, l7 = lane & 7;

  // stage source: pre-swizzled global address (16B slot ^= row&7), linear LDS dest
  int lrow = lane >> 3;
  int lcol = ((lane & 7) ^ lrow) * 8;
  const unsigned short* Abase = A + (size_t)(bm * 256 + lrow) * K + lcol;
  const unsigned short* Bb0 = B0 + (size_t)e * NOUT * K + (size_t)(bn * BNCOL + lrow) * K + lcol;
  const unsigned short* Bb1 = (NW == 2)
      ? B1 + (size_t)e * NOUT * K + (size_t)(bn * BNCOL + lrow) * K + lcol : Bb0;

  auto STAGE = [&](int ktile, int buf) {
    char* lb = smem + buf * BUFSZ;
#pragma unroll
    for (int i = 0; i < CPW; ++i) {
      int c = wid * CPW + i;
      if (c < 32) {
        const unsigned short* g = Abase + (size_t)(c * 8) * K + ktile * 64;
        __builtin_amdgcn_global_load_lds((const __attribute__((address_space(1))) void*)g,
                                         (__attribute__((address_space(3))) void*)(lb + c * 1024), 16, 0, 0);
      } else {
        int cb2 = c - 32;
        const unsigned short* base = (cb2 >> 4) ? Bb1 : Bb0;
        const unsigned short* g = base + (size_t)((cb2 & 15) * 8) * K + ktile * 64;
        __builtin_amdgcn_global_load_lds((const __attribute__((address_space(1))) void*)g,
                                         (__attribute__((address_space(3))) void*)(lb + ABYTES + cb2 * 1024), 16, 0, 0);
      }
    }
  };

  // swizzled ds_read slot offsets (same involution)
  int sw0 = ((0 + lhi) ^ l7) * 16;
  int sw1 = ((4 + lhi) ^ l7) * 16;

  f32x4 acc[8][NW][2] = {};

  // ---- prologue: stage tiles kt0, kt0+1 ----
  STAGE(kt0, 0);
  STAGE(kt0 + 1, 1);
  waitv<CPW>();
  __builtin_amdgcn_sched_barrier(0);
  __builtin_amdgcn_s_barrier();
  __builtin_amdgcn_sched_barrier(0);

  for (int ktl = 0; ktl < KTS; ++ktl) {
    char* cb = smem + (ktl & 1) * BUFSZ;
    short8 a0[8], b0[NW][2], a1[8], b1[NW][2];
#pragma unroll
    for (int w = 0; w < NW; ++w)
#pragma unroll
      for (int n = 0; n < 2; ++n)
        b0[w][n] = *(const short8*)(cb + ABYTES + w * 16384 + wc * 4096 + n * 2048 + lane15 * 128 + sw0);
#pragma unroll
    for (int m = 0; m < 8; ++m)
      a0[m] = *(const short8*)(cb + wr * 16384 + m * 2048 + lane15 * 128 + sw0);
    __builtin_amdgcn_s_setprio(1);
#pragma unroll
    for (int m = 0; m < 8; ++m)
#pragma unroll
      for (int w = 0; w < NW; ++w)
#pragma unroll
        for (int n = 0; n < 2; ++n)
          acc[m][w][n] = __builtin_amdgcn_mfma_f32_16x16x32_bf16(a0[m], b0[w][n], acc[m][w][n], 0, 0, 0);
    __builtin_amdgcn_s_setprio(0);
#pragma unroll
    for (int w = 0; w < NW; ++w)
#pragma unroll
      for (int n = 0; n < 2; ++n)
        b1[w][n] = *(const short8*)(cb + ABYTES + w * 16384 + wc * 4096 + n * 2048 + lane15 * 128 + sw1);
#pragma unroll
    for (int m = 0; m < 8; ++m)
      a1[m] = *(const short8*)(cb + wr * 16384 + m * 2048 + lane15 * 128 + sw1);
    // all ds_reads of this buffer issued -> safe to overwrite after barrier
    __builtin_amdgcn_sched_barrier(0);
    __builtin_amdgcn_s_barrier();
    __builtin_amdgcn_sched_barrier(0);
    if (ktl + 2 < KTS) STAGE(kt0 + ktl + 2, ktl & 1);
    __builtin_amdgcn_s_setprio(1);
#pragma unroll
    for (int m = 0; m < 8; ++m)
#pragma unroll
      for (int w = 0; w < NW; ++w)
#pragma unroll
        for (int n = 0; n < 2; ++n)
          acc[m][w][n] = __builtin_amdgcn_mfma_f32_16x16x32_bf16(a1[m], b1[w][n], acc[m][w][n], 0, 0, 0);
    __builtin_amdgcn_s_setprio(0);
    if (ktl + 2 < KTS) waitv<CPW>();
    else if (ktl + 1 < KTS) waitv<0>();
    __builtin_amdgcn_sched_barrier(0);
    if (ktl + 1 < KTS) __builtin_amdgcn_s_barrier();
    __builtin_amdgcn_sched_barrier(0);
  }

  // ---- epilogue ----
  if constexpr (MODE == 1) {
    unsigned short* H = (unsigned short*)OUT + (size_t)e * CAP * NOUT;
#pragma unroll
    for (int m = 0; m < 8; ++m) {
#pragma unroll
      for (int n = 0; n < 2; ++n) {
        int row0 = bm * 256 + wr * 128 + m * 16 + lhi * 4;
        int col = bn * 128 + wc * 32 + n * 16 + lane15;
#pragma unroll
        for (int j = 0; j < 4; ++j) {
          float g1 = acc[m][0][n][j];
          float g3 = acc[m][1][n][j];
          float hv = g1 / (1.0f + __expf(-g1)) * g3;
          H[(size_t)(row0 + j) * NOUT + col] = f2bf(hv);
        }
      }
    }
    // w2 drip: this block's 32768-float slice (WELEM = 704 * 32768 exactly)
    {
      size_t base = (size_t)lid * 32768;
      const float* s = W2src + base;
      unsigned short* d = WB2dst + base;
#pragma unroll
      for (int i = 0; i < 16; ++i) {
        size_t o = (size_t)(i * 512 + tid) * 4;
        float4 v = *(const float4*)(s + o);
        *(ushort4*)(d + o) = make_ushort4(f2bf(v.x), f2bf(v.y), f2bf(v.z), f2bf(v.w));
      }
    }
  } else {
    // ungated split-K partial: one writer per (sk, e, row, col)
    float* P = (float*)OUT + (size_t)sk * 8 * CAP * NOUT + (size_t)e * CAP * NOUT;
#pragma unroll
    for (int m = 0; m < 8; ++m) {
#pragma unroll
      for (int w = 0; w < NW; ++w) {
#pragma unroll
        for (int n = 0; n < 2; ++n) {
          int row0 = bm * 256 + wr * 128 + m * 16 + lhi * 4;
          int col = bn * BNCOL + w * 128 + wc * 32 + n * 16 + lane15;
#pragma unroll
          for (int j = 0; j < 4; ++j)
            P[(size_t)(row0 + j) * NOUT + col] = acc[m][w][n][j];
        }
      }
    }
  }
}

// ---------------- combine: out[t] = sum_k g_k * (P0[e_k,s_k] + P1[e_k,s_k]) ----------------
__global__ void combine_kernel(const float* __restrict__ ob, const int* __restrict__ topi,
                               const float* __restrict__ gall, const int* __restrict__ slot,
                               float* __restrict__ out) {
  int t = blockIdx.x;
  int d = threadIdx.x * 4;
  const size_t HALF = (size_t)8 * CAP * D_MODEL;
  float4 r = make_float4(0.f, 0.f, 0.f, 0.f);
#pragma unroll
  for (int k = 0; k < 2; ++k) {
    int s = slot[t * 2 + k];
    if (s >= 0) {
      int e = topi[t * 2 + k];
      float g = gall[t * 2 + k];
      size_t base = ((size_t)e * CAP + s) * D_MODEL + d;
      float4 a = *(const float4*)(ob + base);
      float4 b = *(const float4*)(ob + HALF + base);
      r.x += g * (a.x + b.x); r.y += g * (a.y + b.y);
      r.z += g * (a.z + b.z); r.w += g * (a.w + b.w);
    }
  }
  *(float4*)(out + (size_t)t * D_MODEL + d) = r;
}

extern "C" void kernel_launch(void* const* d_in, const int* in_sizes, int n_in,
                              void* d_out, int out_size, void* d_ws, size_t ws_size,
                              hipStream_t stream) {
  const float* x     = (const float*)d_in[0];
  const float* noise = (const float*)d_in[1];
  const float* rw    = (const float*)d_in[2];
  const float* rb    = (const float*)d_in[3];
  const float* nw    = (const float*)d_in[4];
  const float* nb    = (const float*)d_in[5];
  const float* w1    = (const float*)d_in[6];
  const float* w3    = (const float*)d_in[7];
  const float* w2    = (const float*)d_in[8];
  float* out = (float*)d_out;

  char* ws = (char*)d_ws;
  size_t off = 0;
  auto alloc = [&](size_t bytes) -> void* {
    void* p = ws + off;
    off += (bytes + 255) & ~(size_t)255;
    return p;
  };
  const size_t WELEM = (size_t)8 * HIDDEN * D_MODEL;          // 23,068,672 = 704 * 32768
  unsigned short* wb1 = (unsigned short*)alloc(WELEM * 2);
  unsigned short* wb3 = (unsigned short*)alloc(WELEM * 2);
  unsigned short* wb2 = (unsigned short*)alloc(WELEM * 2);
  unsigned short* xb  = (unsigned short*)alloc((size_t)8 * CAP * D_MODEL * 2);
  unsigned short* h   = (unsigned short*)alloc((size_t)8 * CAP * HIDDEN * 2);
  float*          ob  = (float*)alloc((size_t)2 * 8 * CAP * D_MODEL * 4);  // 2 split-K partials
  int*   topi  = (int*)alloc(N_TOK * 2 * 4);
  float* gall  = (float*)alloc(N_TOK * 2 * 4);
  int*   slot  = (int*)alloc(N_TOK * 2 * 4);
  int*   tokl  = (int*)alloc(8 * CAP * 4);
  (void)ws_size; (void)in_sizes; (void)n_in; (void)out_size;

  router_kernel<<<N_TOK / 4, 256, 0, stream>>>(x, noise, rw, rb, nw, nb, topi, gall, slot);
  scan_kernel<<<8, 1024, 0, stream>>>(topi, slot, tokl);

  // gather (8192 blocks) + cvt w1/w3 (45056 blocks) in one dispatch
  const int cvt12_blocks = (int)(2 * WELEM / 4 / 256);   // 45056
  gather_cvt_kernel<<<8192 + cvt12_blocks, 256, 0, stream>>>(x, tokl, xb, w1, w3, wb1, wb3);

  // FUSE GEMM12 + silu + w2-drip: h = silu(xb@w1^T)*(xb@w3^T); wb2 = bf16(w2). 704 wgs.
  gemm_moe<HIDDEN, D_MODEL, 2, 1><<<dim3(704), 512, 0, stream>>>(
      xb, wb1, wb3, (void*)h, w2, wb2);

  // PART GEMM3: ob[sk] = h @ w2^T partials. BN=256, split-K2: 256 wgs.
  gemm_moe<D_MODEL, HIDDEN, 2, 2><<<dim3(256), 512, 0, stream>>>(
      h, wb2, wb2 + (size_t)128 * HIDDEN, (void*)ob, nullptr, nullptr);

  // combine partials with gates; plain stores (no memset needed)
  combine_kernel<<<N_TOK, 256, 0, stream>>>(ob, topi, gall, slot, out);
}

// Round 12
// 320.911 us; speedup vs baseline: 1.0174x; 1.0174x over previous
//
#include <hip/hip_runtime.h>

// SparseMoE: B=2,S=2048 -> N=4096 tokens, D=1024, HIDDEN=2816, 8 experts, top-2, cap=1024
// Round 12: r6 structure (all components at measured best), cvt3 store width fixed:
// 8B ushort4 stores (512B/wave, ~4 TB/s) -> 16B short8 stores (1KB/wave). Ledger:
//  - GEMM12 clean (precvt bf16 + gload_lds): 113us = m248 structural ceiling. Drips hurt (r11).
//  - GEMM3 split-K2 + partial stores: ~56us. Atomic scatter cost +60us (r5).
//  - In-GEMM f32 B: +60/+30us (r7) or spill (r3/r8: acc=128 AGPRs caps arch VGPR at 128).
//  - Merging router with anything: joint-regalloc starvation (r9/r10).

#define D_MODEL 1024
#define HIDDEN 2816
#define N_TOK 4096
#define CAP 1024

typedef __attribute__((ext_vector_type(8))) short short8;
typedef __attribute__((ext_vector_type(4))) float f32x4;

__device__ __forceinline__ unsigned short f2bf(float f) {
  unsigned int u = __float_as_uint(f);
  u += 0x7fffu + ((u >> 16) & 1u);   // RNE
  return (unsigned short)(u >> 16);
}
__device__ __forceinline__ float bf2f(unsigned short h) {
  return __uint_as_float(((unsigned int)h) << 16);
}

template <int Ncnt> __device__ __forceinline__ void waitv() {
  if constexpr (Ncnt == 8)      asm volatile("s_waitcnt vmcnt(8)" ::: "memory");
  else if constexpr (Ncnt == 6) asm volatile("s_waitcnt vmcnt(6)" ::: "memory");
  else                          asm volatile("s_waitcnt vmcnt(0)" ::: "memory");
}

// ---------------- router: logits, noisy top-2, gates ----------------
__global__ void router_kernel(const float* __restrict__ x, const float* __restrict__ noise,
                              const float* __restrict__ rw, const float* __restrict__ rb,
                              const float* __restrict__ nw, const float* __restrict__ nb,
                              int* __restrict__ topi, float* __restrict__ gall,
                              int* __restrict__ slot) {
  int wid = threadIdx.x >> 6;
  int lane = threadIdx.x & 63;
  int t = blockIdx.x * 4 + wid;
  if (t >= N_TOK) return;
  const float* xr = x + (size_t)t * D_MODEL;
  double accL[8] = {0,0,0,0,0,0,0,0};
  double accN[8] = {0,0,0,0,0,0,0,0};
  for (int i = 0; i < 4; ++i) {
    int kb = (i * 64 + lane) * 4;
    float4 xv = *(const float4*)(xr + kb);
#pragma unroll
    for (int e = 0; e < 8; ++e) {
      float4 wv = *(const float4*)(rw + e * D_MODEL + kb);
      accL[e] += (double)xv.x * wv.x + (double)xv.y * wv.y + (double)xv.z * wv.z + (double)xv.w * wv.w;
      float4 nv = *(const float4*)(nw + e * D_MODEL + kb);
      accN[e] += (double)xv.x * nv.x + (double)xv.y * nv.y + (double)xv.z * nv.z + (double)xv.w * nv.w;
    }
  }
#pragma unroll
  for (int e = 0; e < 8; ++e) {
    for (int s = 32; s > 0; s >>= 1) {
      accL[e] += __shfl_xor(accL[e], s);
      accN[e] += __shfl_xor(accN[e], s);
    }
  }
  if (lane == 0) {
    double noisy[8];
#pragma unroll
    for (int e = 0; e < 8; ++e) {
      double lg = accL[e] + (double)rb[e];
      double nl = accN[e] + (double)nb[e];
      double sp = (nl > 0.0 ? nl : 0.0) + log1p(exp(-fabs(nl)));  // softplus, stable
      noisy[e] = lg + (double)noise[t * 8 + e] * sp;
    }
    int i0 = 0;
    for (int e = 1; e < 8; ++e) if (noisy[e] > noisy[i0]) i0 = e;
    int i1 = -1;
    for (int e = 0; e < 8; ++e) { if (e == i0) continue; if (i1 < 0 || noisy[e] > noisy[i1]) i1 = e; }
    double g0 = 1.0 / (1.0 + exp(noisy[i1] - noisy[i0]));
    topi[t * 2] = i0; topi[t * 2 + 1] = i1;
    gall[t * 2] = (float)g0; gall[t * 2 + 1] = (float)(1.0 - g0);
    slot[t * 2] = -1; slot[t * 2 + 1] = -1;
  }
}

// ---------------- per-expert capacity scan (token-index order) ----------------
__global__ void scan_kernel(const int* __restrict__ topi,
                            int* __restrict__ slot, int* __restrict__ tok_list) {
  int e = blockIdx.x;
  int tid = threadIdx.x;
  int lane = tid & 63, wid = tid >> 6;
  __shared__ int wsum[16];
  __shared__ int base_s;
  tok_list[e * CAP + tid] = -1;
  if (tid == 0) base_s = 0;
  __syncthreads();
  for (int chunk = 0; chunk < N_TOK / 1024; ++chunk) {
    int t = chunk * 1024 + tid;
    int i0 = topi[t * 2], i1 = topi[t * 2 + 1];
    bool m = (i0 == e) || (i1 == e);
    unsigned long long mask = __ballot(m);
    int excl = __popcll(mask & ((1ull << lane) - 1ull));
    if (lane == 0) wsum[wid] = __popcll(mask);
    __syncthreads();
    int base = base_s;
    int woff = 0;
    for (int w = 0; w < wid; ++w) woff += wsum[w];
    int pos = base + woff + excl;
    if (m && pos < CAP) {
      tok_list[e * CAP + pos] = t;
      if (i0 == e) slot[t * 2] = pos; else slot[t * 2 + 1] = pos;
    }
    __syncthreads();
    if (tid == 0) {
      int s = 0;
      for (int w = 0; w < 16; ++w) s += wsum[w];
      base_s = base + s;
    }
    __syncthreads();
  }
}

// ---------------- gather x rows into per-expert bf16 buffers ----------------
__global__ void gather_kernel(const float* __restrict__ x, const int* __restrict__ tok_list,
                              unsigned short* __restrict__ xb) {
  int row = blockIdx.x;
  int tok = tok_list[row];
  unsigned short* dst = xb + (size_t)row * D_MODEL + threadIdx.x * 4;
  if (tok < 0) {
    *(ushort4*)dst = make_ushort4(0, 0, 0, 0);
  } else {
    float4 v = *(const float4*)(x + (size_t)tok * D_MODEL + threadIdx.x * 4);
    *(ushort4*)dst = make_ushort4(f2bf(v.x), f2bf(v.y), f2bf(v.z), f2bf(v.w));
  }
}

// ---------------- f32 -> bf16 weight convert: 8 floats/thread, 16B stores ----------------
__global__ void cvt3_kernel(const float* __restrict__ s0, const float* __restrict__ s1,
                            const float* __restrict__ s2, unsigned short* __restrict__ d0,
                            unsigned short* __restrict__ d1, unsigned short* __restrict__ d2) {
  size_t i = (size_t)blockIdx.x * 256 + threadIdx.x;
  const float* src = (blockIdx.y == 0) ? s0 : (blockIdx.y == 1) ? s1 : s2;
  unsigned short* dst = (blockIdx.y == 0) ? d0 : (blockIdx.y == 1) ? d1 : d2;
  float4 a = *(const float4*)(src + i * 8);
  float4 b = *(const float4*)(src + i * 8 + 4);
  short8 v;
  v[0] = (short)f2bf(a.x); v[1] = (short)f2bf(a.y);
  v[2] = (short)f2bf(a.z); v[3] = (short)f2bf(a.w);
  v[4] = (short)f2bf(b.x); v[5] = (short)f2bf(b.y);
  v[6] = (short)f2bf(b.z); v[7] = (short)f2bf(b.w);
  *(short8*)(dst + i * 8) = v;   // 16B/lane store
}

// ============ grouped GEMM core (gload_lds + src-swizzle + counted vmcnt) ============
// BM=256, 8 waves (2M x 4N), NW B-panels of 128 cols each, optional split-K.
// MODE 1 (FUSE): panels = w1,w3 at same cols; epilogue silu(acc0)*acc1 -> bf16 h.
// MODE 2 (PART): panels = adjacent 128-col halves of w2 (BNCOL=256), split-K SK=2;
//                epilogue stores ungated f32 partials (no atomics).
template <int NOUT, int K, int NW, int MODE>
__global__ __launch_bounds__(512, 1)
void gemm_moe(const unsigned short* __restrict__ Ab, const unsigned short* __restrict__ B0,
              const unsigned short* __restrict__ B1, void* __restrict__ OUT) {
  constexpr int ABYTES = 32768;
  constexpr int BUFSZ = ABYTES + NW * 16384;
  constexpr int KT = K / 64;
  constexpr int SK = (MODE == 2) ? 2 : 1;
  constexpr int KTS = KT / SK;
  constexpr int BNCOL = (MODE == 2 && NW == 2) ? 256 : 128;
  constexpr int NBN = NOUT / BNCOL;
  constexpr int NWG = 8 * 4 * NBN * SK;
  constexpr int CPW = (32 + NW * 16) / 8;   // gload_lds per thread per stage: 8 or 6

  __shared__ char smem[2 * BUFSZ];

  // bijective XCD swizzle + decode (NWG % 8 == 0)
  int lid = blockIdx.x;
  int swz = (lid & 7) * (NWG / 8) + (lid >> 3);
  constexpr int PERE = 4 * NBN * SK;
  int e = swz / PERE;
  int r = swz - e * PERE;
  int bm = r / (NBN * SK);
  int r2 = r - bm * (NBN * SK);
  int bn = r2 / SK;
  int sk = r2 - bn * SK;
  int kt0 = sk * KTS;

  const unsigned short* A = Ab + (size_t)e * CAP * K;
  int tid = threadIdx.x, lane = tid & 63, wid = tid >> 6;
  int wr = wid >> 2, wc = wid & 3;
  int lane15 = lane & 15, lhi = lane >> 4, l7 = lane & 7;

  // stage source: pre-swizzled global address (16B slot ^= row&7), linear LDS dest
  int lrow = lane >> 3;
  int lcol = ((lane & 7) ^ lrow) * 8;
  const unsigned short* Abase = A + (size_t)(bm * 256 + lrow) * K + lcol;
  const unsigned short* Bb0 = B0 + (size_t)e * NOUT * K + (size_t)(bn * BNCOL + lrow) * K + lcol;
  const unsigned short* Bb1 = (NW == 2)
      ? B1 + (size_t)e * NOUT * K + (size_t)(bn * BNCOL + lrow) * K + lcol : Bb0;

  auto STAGE = [&](int ktile, int buf) {
    char* lb = smem + buf * BUFSZ;
#pragma unroll
    for (int i = 0; i < CPW; ++i) {
      int c = wid * CPW + i;
      if (c < 32) {
        const unsigned short* g = Abase + (size_t)(c * 8) * K + ktile * 64;
        __builtin_amdgcn_global_load_lds((const __attribute__((address_space(1))) void*)g,
                                         (__attribute__((address_space(3))) void*)(lb + c * 1024), 16, 0, 0);
      } else {
        int cb2 = c - 32;
        const unsigned short* base = (cb2 >> 4) ? Bb1 : Bb0;
        const unsigned short* g = base + (size_t)((cb2 & 15) * 8) * K + ktile * 64;
        __builtin_amdgcn_global_load_lds((const __attribute__((address_space(1))) void*)g,
                                         (__attribute__((address_space(3))) void*)(lb + ABYTES + cb2 * 1024), 16, 0, 0);
      }
    }
  };

  // swizzled ds_read slot offsets (same involution)
  int sw0 = ((0 + lhi) ^ l7) * 16;
  int sw1 = ((4 + lhi) ^ l7) * 16;

  f32x4 acc[8][NW][2] = {};

  // ---- prologue: stage tiles kt0, kt0+1 ----
  STAGE(kt0, 0);
  STAGE(kt0 + 1, 1);
  waitv<CPW>();
  __builtin_amdgcn_sched_barrier(0);
  __builtin_amdgcn_s_barrier();
  __builtin_amdgcn_sched_barrier(0);

  for (int ktl = 0; ktl < KTS; ++ktl) {
    char* cb = smem + (ktl & 1) * BUFSZ;
    short8 a0[8], b0[NW][2], a1[8], b1[NW][2];
#pragma unroll
    for (int w = 0; w < NW; ++w)
#pragma unroll
      for (int n = 0; n < 2; ++n)
        b0[w][n] = *(const short8*)(cb + ABYTES + w * 16384 + wc * 4096 + n * 2048 + lane15 * 128 + sw0);
#pragma unroll
    for (int m = 0; m < 8; ++m)
      a0[m] = *(const short8*)(cb + wr * 16384 + m * 2048 + lane15 * 128 + sw0);
    __builtin_amdgcn_s_setprio(1);
#pragma unroll
    for (int m = 0; m < 8; ++m)
#pragma unroll
      for (int w = 0; w < NW; ++w)
#pragma unroll
        for (int n = 0; n < 2; ++n)
          acc[m][w][n] = __builtin_amdgcn_mfma_f32_16x16x32_bf16(a0[m], b0[w][n], acc[m][w][n], 0, 0, 0);
    __builtin_amdgcn_s_setprio(0);
#pragma unroll
    for (int w = 0; w < NW; ++w)
#pragma unroll
      for (int n = 0; n < 2; ++n)
        b1[w][n] = *(const short8*)(cb + ABYTES + w * 16384 + wc * 4096 + n * 2048 + lane15 * 128 + sw1);
#pragma unroll
    for (int m = 0; m < 8; ++m)
      a1[m] = *(const short8*)(cb + wr * 16384 + m * 2048 + lane15 * 128 + sw1);
    // all ds_reads of this buffer issued -> safe to overwrite after barrier
    __builtin_amdgcn_sched_barrier(0);
    __builtin_amdgcn_s_barrier();
    __builtin_amdgcn_sched_barrier(0);
    if (ktl + 2 < KTS) STAGE(kt0 + ktl + 2, ktl & 1);
    __builtin_amdgcn_s_setprio(1);
#pragma unroll
    for (int m = 0; m < 8; ++m)
#pragma unroll
      for (int w = 0; w < NW; ++w)
#pragma unroll
        for (int n = 0; n < 2; ++n)
          acc[m][w][n] = __builtin_amdgcn_mfma_f32_16x16x32_bf16(a1[m], b1[w][n], acc[m][w][n], 0, 0, 0);
    __builtin_amdgcn_s_setprio(0);
    if (ktl + 2 < KTS) waitv<CPW>();
    else if (ktl + 1 < KTS) waitv<0>();
    __builtin_amdgcn_sched_barrier(0);
    if (ktl + 1 < KTS) __builtin_amdgcn_s_barrier();
    __builtin_amdgcn_sched_barrier(0);
  }

  // ---- epilogue ----
  if constexpr (MODE == 1) {
    unsigned short* H = (unsigned short*)OUT + (size_t)e * CAP * NOUT;
#pragma unroll
    for (int m = 0; m < 8; ++m) {
#pragma unroll
      for (int n = 0; n < 2; ++n) {
        int row0 = bm * 256 + wr * 128 + m * 16 + lhi * 4;
        int col = bn * 128 + wc * 32 + n * 16 + lane15;
#pragma unroll
        for (int j = 0; j < 4; ++j) {
          float g1 = acc[m][0][n][j];
          float g3 = acc[m][1][n][j];
          float hv = g1 / (1.0f + __expf(-g1)) * g3;
          H[(size_t)(row0 + j) * NOUT + col] = f2bf(hv);
        }
      }
    }
  } else {
    // ungated split-K partial: one writer per (sk, e, row, col)
    float* P = (float*)OUT + (size_t)sk * 8 * CAP * NOUT + (size_t)e * CAP * NOUT;
#pragma unroll
    for (int m = 0; m < 8; ++m) {
#pragma unroll
      for (int w = 0; w < NW; ++w) {
#pragma unroll
        for (int n = 0; n < 2; ++n) {
          int row0 = bm * 256 + wr * 128 + m * 16 + lhi * 4;
          int col = bn * BNCOL + w * 128 + wc * 32 + n * 16 + lane15;
#pragma unroll
          for (int j = 0; j < 4; ++j)
            P[(size_t)(row0 + j) * NOUT + col] = acc[m][w][n][j];
        }
      }
    }
  }
}

// ---------------- combine: out[t] = sum_k g_k * (P0[e_k,s_k] + P1[e_k,s_k]) ----------------
__global__ void combine_kernel(const float* __restrict__ ob, const int* __restrict__ topi,
                               const float* __restrict__ gall, const int* __restrict__ slot,
                               float* __restrict__ out) {
  int t = blockIdx.x;
  int d = threadIdx.x * 4;
  const size_t HALF = (size_t)8 * CAP * D_MODEL;
  float4 r = make_float4(0.f, 0.f, 0.f, 0.f);
#pragma unroll
  for (int k = 0; k < 2; ++k) {
    int s = slot[t * 2 + k];
    if (s >= 0) {
      int e = topi[t * 2 + k];
      float g = gall[t * 2 + k];
      size_t base = ((size_t)e * CAP + s) * D_MODEL + d;
      float4 a = *(const float4*)(ob + base);
      float4 b = *(const float4*)(ob + HALF + base);
      r.x += g * (a.x + b.x); r.y += g * (a.y + b.y);
      r.z += g * (a.z + b.z); r.w += g * (a.w + b.w);
    }
  }
  *(float4*)(out + (size_t)t * D_MODEL + d) = r;
}

extern "C" void kernel_launch(void* const* d_in, const int* in_sizes, int n_in,
                              void* d_out, int out_size, void* d_ws, size_t ws_size,
                              hipStream_t stream) {
  const float* x     = (const float*)d_in[0];
  const float* noise = (const float*)d_in[1];
  const float* rw    = (const float*)d_in[2];
  const float* rb    = (const float*)d_in[3];
  const float* nw    = (const float*)d_in[4];
  const float* nb    = (const float*)d_in[5];
  const float* w1    = (const float*)d_in[6];
  const float* w3    = (const float*)d_in[7];
  const float* w2    = (const float*)d_in[8];
  float* out = (float*)d_out;

  char* ws = (char*)d_ws;
  size_t off = 0;
  auto alloc = [&](size_t bytes) -> void* {
    void* p = ws + off;
    off += (bytes + 255) & ~(size_t)255;
    return p;
  };
  const size_t WELEM = (size_t)8 * HIDDEN * D_MODEL;   // 23,068,672
  unsigned short* wb1 = (unsigned short*)alloc(WELEM * 2);
  unsigned short* wb3 = (unsigned short*)alloc(WELEM * 2);
  unsigned short* wb2 = (unsigned short*)alloc(WELEM * 2);
  unsigned short* xb  = (unsigned short*)alloc((size_t)8 * CAP * D_MODEL * 2);
  unsigned short* h   = (unsigned short*)alloc((size_t)8 * CAP * HIDDEN * 2);
  float*          ob  = (float*)alloc((size_t)2 * 8 * CAP * D_MODEL * 4);  // 2 split-K partials
  int*   topi  = (int*)alloc(N_TOK * 2 * 4);
  float* gall  = (float*)alloc(N_TOK * 2 * 4);
  int*   slot  = (int*)alloc(N_TOK * 2 * 4);
  int*   tokl  = (int*)alloc(8 * CAP * 4);
  (void)ws_size; (void)in_sizes; (void)n_in; (void)out_size;

  // cvt3: 8 floats/thread, 16B bf16 stores. WELEM/8/256 = 11264 blocks per array.
  cvt3_kernel<<<dim3((unsigned)(WELEM / 8 / 256), 3), 256, 0, stream>>>(
      w1, w3, w2, wb1, wb3, wb2);

  router_kernel<<<N_TOK / 4, 256, 0, stream>>>(x, noise, rw, rb, nw, nb, topi, gall, slot);
  scan_kernel<<<8, 1024, 0, stream>>>(topi, slot, tokl);
  gather_kernel<<<8 * CAP, 256, 0, stream>>>(x, tokl, xb);

  // FUSE GEMM12 + silu: h = silu(xb@w1^T) * (xb@w3^T), bf16. 8e*4bm*22bn = 704 wgs.
  gemm_moe<HIDDEN, D_MODEL, 2, 1><<<dim3(704), 512, 0, stream>>>(xb, wb1, wb3, (void*)h);

  // PART GEMM3: ob[sk] = h @ w2^T partials. BN=256, split-K2: 256 wgs.
  gemm_moe<D_MODEL, HIDDEN, 2, 2><<<dim3(256), 512, 0, stream>>>(
      h, wb2, wb2 + (size_t)128 * HIDDEN, (void*)ob);

  // combine partials with gates; plain stores (no memset needed)
  combine_kernel<<<N_TOK, 256, 0, stream>>>(ob, topi, gall, slot, out);
}

// Round 14
// 298.969 us; speedup vs baseline: 1.0920x; 1.0734x over previous
//
#include <hip/hip_runtime.h>

// SparseMoE: B=2,S=2048 -> N=4096 tokens, D=1024, HIDDEN=2816, 8 experts, top-2, cap=1024
// Round 14: round-13 with the compile fix (__builtin_nontemporal_* needs ext_vector
// pointers, not HIP_vector_type). Changes vs r12 remain:
//  (1) bm-fastest block decode: B-panel sharers (4 bm) co-XCD -> staging L2-hits.
//  (2) cvt3 non-temporal loads/stores (suspect: L2 write-allocate capping cvt at ~4 TB/s).
//  (3) GEMM3 bf16 split-K partials (-64 MB ob traffic).

#define D_MODEL 1024
#define HIDDEN 2816
#define N_TOK 4096
#define CAP 1024

typedef __attribute__((ext_vector_type(8))) short short8;
typedef __attribute__((ext_vector_type(4))) float f32x4;

__device__ __forceinline__ unsigned short f2bf(float f) {
  unsigned int u = __float_as_uint(f);
  u += 0x7fffu + ((u >> 16) & 1u);   // RNE
  return (unsigned short)(u >> 16);
}
__device__ __forceinline__ float bf2f(unsigned short h) {
  return __uint_as_float(((unsigned int)h) << 16);
}

template <int Ncnt> __device__ __forceinline__ void waitv() {
  if constexpr (Ncnt == 8)      asm volatile("s_waitcnt vmcnt(8)" ::: "memory");
  else if constexpr (Ncnt == 6) asm volatile("s_waitcnt vmcnt(6)" ::: "memory");
  else                          asm volatile("s_waitcnt vmcnt(0)" ::: "memory");
}

// ---------------- router: logits, noisy top-2, gates ----------------
__global__ void router_kernel(const float* __restrict__ x, const float* __restrict__ noise,
                              const float* __restrict__ rw, const float* __restrict__ rb,
                              const float* __restrict__ nw, const float* __restrict__ nb,
                              int* __restrict__ topi, float* __restrict__ gall,
                              int* __restrict__ slot) {
  int wid = threadIdx.x >> 6;
  int lane = threadIdx.x & 63;
  int t = blockIdx.x * 4 + wid;
  if (t >= N_TOK) return;
  const float* xr = x + (size_t)t * D_MODEL;
  double accL[8] = {0,0,0,0,0,0,0,0};
  double accN[8] = {0,0,0,0,0,0,0,0};
  for (int i = 0; i < 4; ++i) {
    int kb = (i * 64 + lane) * 4;
    float4 xv = *(const float4*)(xr + kb);
#pragma unroll
    for (int e = 0; e < 8; ++e) {
      float4 wv = *(const float4*)(rw + e * D_MODEL + kb);
      accL[e] += (double)xv.x * wv.x + (double)xv.y * wv.y + (double)xv.z * wv.z + (double)xv.w * wv.w;
      float4 nv = *(const float4*)(nw + e * D_MODEL + kb);
      accN[e] += (double)xv.x * nv.x + (double)xv.y * nv.y + (double)xv.z * nv.z + (double)xv.w * nv.w;
    }
  }
#pragma unroll
  for (int e = 0; e < 8; ++e) {
    for (int s = 32; s > 0; s >>= 1) {
      accL[e] += __shfl_xor(accL[e], s);
      accN[e] += __shfl_xor(accN[e], s);
    }
  }
  if (lane == 0) {
    double noisy[8];
#pragma unroll
    for (int e = 0; e < 8; ++e) {
      double lg = accL[e] + (double)rb[e];
      double nl = accN[e] + (double)nb[e];
      double sp = (nl > 0.0 ? nl : 0.0) + log1p(exp(-fabs(nl)));  // softplus, stable
      noisy[e] = lg + (double)noise[t * 8 + e] * sp;
    }
    int i0 = 0;
    for (int e = 1; e < 8; ++e) if (noisy[e] > noisy[i0]) i0 = e;
    int i1 = -1;
    for (int e = 0; e < 8; ++e) { if (e == i0) continue; if (i1 < 0 || noisy[e] > noisy[i1]) i1 = e; }
    double g0 = 1.0 / (1.0 + exp(noisy[i1] - noisy[i0]));
    topi[t * 2] = i0; topi[t * 2 + 1] = i1;
    gall[t * 2] = (float)g0; gall[t * 2 + 1] = (float)(1.0 - g0);
    slot[t * 2] = -1; slot[t * 2 + 1] = -1;
  }
}

// ---------------- per-expert capacity scan (token-index order) ----------------
__global__ void scan_kernel(const int* __restrict__ topi,
                            int* __restrict__ slot, int* __restrict__ tok_list) {
  int e = blockIdx.x;
  int tid = threadIdx.x;
  int lane = tid & 63, wid = tid >> 6;
  __shared__ int wsum[16];
  __shared__ int base_s;
  tok_list[e * CAP + tid] = -1;
  if (tid == 0) base_s = 0;
  __syncthreads();
  for (int chunk = 0; chunk < N_TOK / 1024; ++chunk) {
    int t = chunk * 1024 + tid;
    int i0 = topi[t * 2], i1 = topi[t * 2 + 1];
    bool m = (i0 == e) || (i1 == e);
    unsigned long long mask = __ballot(m);
    int excl = __popcll(mask & ((1ull << lane) - 1ull));
    if (lane == 0) wsum[wid] = __popcll(mask);
    __syncthreads();
    int base = base_s;
    int woff = 0;
    for (int w = 0; w < wid; ++w) woff += wsum[w];
    int pos = base + woff + excl;
    if (m && pos < CAP) {
      tok_list[e * CAP + pos] = t;
      if (i0 == e) slot[t * 2] = pos; else slot[t * 2 + 1] = pos;
    }
    __syncthreads();
    if (tid == 0) {
      int s = 0;
      for (int w = 0; w < 16; ++w) s += wsum[w];
      base_s = base + s;
    }
    __syncthreads();
  }
}

// ---------------- gather x rows into per-expert bf16 buffers ----------------
__global__ void gather_kernel(const float* __restrict__ x, const int* __restrict__ tok_list,
                              unsigned short* __restrict__ xb) {
  int row = blockIdx.x;
  int tok = tok_list[row];
  unsigned short* dst = xb + (size_t)row * D_MODEL + threadIdx.x * 4;
  if (tok < 0) {
    *(ushort4*)dst = make_ushort4(0, 0, 0, 0);
  } else {
    float4 v = *(const float4*)(x + (size_t)tok * D_MODEL + threadIdx.x * 4);
    *(ushort4*)dst = make_ushort4(f2bf(v.x), f2bf(v.y), f2bf(v.z), f2bf(v.w));
  }
}

// ---------------- f32 -> bf16 weight convert: nontemporal, 8 floats/thread ----------------
__global__ void cvt3_kernel(const float* __restrict__ s0, const float* __restrict__ s1,
                            const float* __restrict__ s2, unsigned short* __restrict__ d0,
                            unsigned short* __restrict__ d1, unsigned short* __restrict__ d2) {
  size_t i = (size_t)blockIdx.x * 256 + threadIdx.x;
  const float* src = (blockIdx.y == 0) ? s0 : (blockIdx.y == 1) ? s1 : s2;
  unsigned short* dst = (blockIdx.y == 0) ? d0 : (blockIdx.y == 1) ? d1 : d2;
  f32x4 a = __builtin_nontemporal_load((const f32x4*)(src + i * 8));
  f32x4 b = __builtin_nontemporal_load((const f32x4*)(src + i * 8 + 4));
  short8 v;
  v[0] = (short)f2bf(a[0]); v[1] = (short)f2bf(a[1]);
  v[2] = (short)f2bf(a[2]); v[3] = (short)f2bf(a[3]);
  v[4] = (short)f2bf(b[0]); v[5] = (short)f2bf(b[1]);
  v[6] = (short)f2bf(b[2]); v[7] = (short)f2bf(b[3]);
  __builtin_nontemporal_store(v, (short8*)(dst + i * 8));   // 16B/lane, bypass L2 alloc
}

// ============ grouped GEMM core (gload_lds + src-swizzle + counted vmcnt) ============
// BM=256, 8 waves (2M x 4N), NW B-panels of 128 cols each, optional split-K.
// Block decode is bm-FASTEST: the 4 bm-sharers of a B panel are consecutive on their
// XCD (lid&7 = XCD) -> B step-slices L2-hit; bn-groups share A slices too.
// MODE 1 (FUSE): panels = w1,w3 at same cols; epilogue silu(acc0)*acc1 -> bf16 h.
// MODE 2 (PART): panels = adjacent 128-col halves of w2 (BNCOL=256), split-K SK=2;
//                epilogue stores ungated bf16 partials (no atomics).
template <int NOUT, int K, int NW, int MODE>
__global__ __launch_bounds__(512, 1)
void gemm_moe(const unsigned short* __restrict__ Ab, const unsigned short* __restrict__ B0,
              const unsigned short* __restrict__ B1, void* __restrict__ OUT) {
  constexpr int ABYTES = 32768;
  constexpr int BUFSZ = ABYTES + NW * 16384;
  constexpr int KT = K / 64;
  constexpr int SK = (MODE == 2) ? 2 : 1;
  constexpr int KTS = KT / SK;
  constexpr int BNCOL = (MODE == 2 && NW == 2) ? 256 : 128;
  constexpr int NBN = NOUT / BNCOL;
  constexpr int NWG = 8 * 4 * NBN * SK;
  constexpr int CPW = (32 + NW * 16) / 8;   // gload_lds per thread per stage: 8 or 6

  __shared__ char smem[2 * BUFSZ];

  // bijective XCD swizzle + bm-fastest decode (NWG % 8 == 0)
  int lid = blockIdx.x;
  int swz = (lid & 7) * (NWG / 8) + (lid >> 3);
  constexpr int PERE = 4 * NBN * SK;
  int e = swz / PERE;
  int r = swz - e * PERE;
  int sk = r / (NBN * 4);          // slowest (0 for MODE 1)
  int r2 = r - sk * (NBN * 4);
  int bn = r2 >> 2;
  int bm = r2 & 3;                 // fastest: bm-quad shares B panel, concurrent on XCD
  int kt0 = sk * KTS;

  const unsigned short* A = Ab + (size_t)e * CAP * K;
  int tid = threadIdx.x, lane = tid & 63, wid = tid >> 6;
  int wr = wid >> 2, wc = wid & 3;
  int lane15 = lane & 15, lhi = lane >> 4, l7 = lane & 7;

  // stage source: pre-swizzled global address (16B slot ^= row&7), linear LDS dest
  int lrow = lane >> 3;
  int lcol = ((lane & 7) ^ lrow) * 8;
  const unsigned short* Abase = A + (size_t)(bm * 256 + lrow) * K + lcol;
  const unsigned short* Bb0 = B0 + (size_t)e * NOUT * K + (size_t)(bn * BNCOL + lrow) * K + lcol;
  const unsigned short* Bb1 = (NW == 2)
      ? B1 + (size_t)e * NOUT * K + (size_t)(bn * BNCOL + lrow) * K + lcol : Bb0;

  auto STAGE = [&](int ktile, int buf) {
    char* lb = smem + buf * BUFSZ;
#pragma unroll
    for (int i = 0; i < CPW; ++i) {
      int c = wid * CPW + i;
      if (c < 32) {
        const unsigned short* g = Abase + (size_t)(c * 8) * K + ktile * 64;
        __builtin_amdgcn_global_load_lds((const __attribute__((address_space(1))) void*)g,
                                         (__attribute__((address_space(3))) void*)(lb + c * 1024), 16, 0, 0);
      } else {
        int cb2 = c - 32;
        const unsigned short* base = (cb2 >> 4) ? Bb1 : Bb0;
        const unsigned short* g = base + (size_t)((cb2 & 15) * 8) * K + ktile * 64;
        __builtin_amdgcn_global_load_lds((const __attribute__((address_space(1))) void*)g,
                                         (__attribute__((address_space(3))) void*)(lb + ABYTES + cb2 * 1024), 16, 0, 0);
      }
    }
  };

  // swizzled ds_read slot offsets (same involution)
  int sw0 = ((0 + lhi) ^ l7) * 16;
  int sw1 = ((4 + lhi) ^ l7) * 16;

  f32x4 acc[8][NW][2] = {};

  // ---- prologue: stage tiles kt0, kt0+1 ----
  STAGE(kt0, 0);
  STAGE(kt0 + 1, 1);
  waitv<CPW>();
  __builtin_amdgcn_sched_barrier(0);
  __builtin_amdgcn_s_barrier();
  __builtin_amdgcn_sched_barrier(0);

  for (int ktl = 0; ktl < KTS; ++ktl) {
    char* cb = smem + (ktl & 1) * BUFSZ;
    short8 a0[8], b0[NW][2], a1[8], b1[NW][2];
#pragma unroll
    for (int w = 0; w < NW; ++w)
#pragma unroll
      for (int n = 0; n < 2; ++n)
        b0[w][n] = *(const short8*)(cb + ABYTES + w * 16384 + wc * 4096 + n * 2048 + lane15 * 128 + sw0);
#pragma unroll
    for (int m = 0; m < 8; ++m)
      a0[m] = *(const short8*)(cb + wr * 16384 + m * 2048 + lane15 * 128 + sw0);
    __builtin_amdgcn_s_setprio(1);
#pragma unroll
    for (int m = 0; m < 8; ++m)
#pragma unroll
      for (int w = 0; w < NW; ++w)
#pragma unroll
        for (int n = 0; n < 2; ++n)
          acc[m][w][n] = __builtin_amdgcn_mfma_f32_16x16x32_bf16(a0[m], b0[w][n], acc[m][w][n], 0, 0, 0);
    __builtin_amdgcn_s_setprio(0);
#pragma unroll
    for (int w = 0; w < NW; ++w)
#pragma unroll
      for (int n = 0; n < 2; ++n)
        b1[w][n] = *(const short8*)(cb + ABYTES + w * 16384 + wc * 4096 + n * 2048 + lane15 * 128 + sw1);
#pragma unroll
    for (int m = 0; m < 8; ++m)
      a1[m] = *(const short8*)(cb + wr * 16384 + m * 2048 + lane15 * 128 + sw1);
    // all ds_reads of this buffer issued -> safe to overwrite after barrier
    __builtin_amdgcn_sched_barrier(0);
    __builtin_amdgcn_s_barrier();
    __builtin_amdgcn_sched_barrier(0);
    if (ktl + 2 < KTS) STAGE(kt0 + ktl + 2, ktl & 1);
    __builtin_amdgcn_s_setprio(1);
#pragma unroll
    for (int m = 0; m < 8; ++m)
#pragma unroll
      for (int w = 0; w < NW; ++w)
#pragma unroll
        for (int n = 0; n < 2; ++n)
          acc[m][w][n] = __builtin_amdgcn_mfma_f32_16x16x32_bf16(a1[m], b1[w][n], acc[m][w][n], 0, 0, 0);
    __builtin_amdgcn_s_setprio(0);
    if (ktl + 2 < KTS) waitv<CPW>();
    else if (ktl + 1 < KTS) waitv<0>();
    __builtin_amdgcn_sched_barrier(0);
    if (ktl + 1 < KTS) __builtin_amdgcn_s_barrier();
    __builtin_amdgcn_sched_barrier(0);
  }

  // ---- epilogue ----
  if constexpr (MODE == 1) {
    unsigned short* H = (unsigned short*)OUT + (size_t)e * CAP * NOUT;
#pragma unroll
    for (int m = 0; m < 8; ++m) {
#pragma unroll
      for (int n = 0; n < 2; ++n) {
        int row0 = bm * 256 + wr * 128 + m * 16 + lhi * 4;
        int col = bn * 128 + wc * 32 + n * 16 + lane15;
#pragma unroll
        for (int j = 0; j < 4; ++j) {
          float g1 = acc[m][0][n][j];
          float g3 = acc[m][1][n][j];
          float hv = g1 / (1.0f + __expf(-g1)) * g3;
          H[(size_t)(row0 + j) * NOUT + col] = f2bf(hv);
        }
      }
    }
  } else {
    // ungated split-K bf16 partial: one writer per (sk, e, row, col)
    unsigned short* P = (unsigned short*)OUT + (size_t)sk * 8 * CAP * NOUT + (size_t)e * CAP * NOUT;
#pragma unroll
    for (int m = 0; m < 8; ++m) {
#pragma unroll
      for (int w = 0; w < NW; ++w) {
#pragma unroll
        for (int n = 0; n < 2; ++n) {
          int row0 = bm * 256 + wr * 128 + m * 16 + lhi * 4;
          int col = bn * BNCOL + w * 128 + wc * 32 + n * 16 + lane15;
#pragma unroll
          for (int j = 0; j < 4; ++j)
            P[(size_t)(row0 + j) * NOUT + col] = f2bf(acc[m][w][n][j]);
        }
      }
    }
  }
}

// ------- combine: out[t] = sum_k g_k * (bf2f(P0[e_k,s_k]) + bf2f(P1[e_k,s_k])) -------
__global__ void combine_kernel(const unsigned short* __restrict__ ob, const int* __restrict__ topi,
                               const float* __restrict__ gall, const int* __restrict__ slot,
                               float* __restrict__ out) {
  int t = blockIdx.x;
  int d = threadIdx.x * 8;            // 128 threads x 8 cols
  const size_t HALF = (size_t)8 * CAP * D_MODEL;
  float r[8] = {};
#pragma unroll
  for (int k = 0; k < 2; ++k) {
    int s = slot[t * 2 + k];
    if (s >= 0) {
      int e = topi[t * 2 + k];
      float g = gall[t * 2 + k];
      size_t base = ((size_t)e * CAP + s) * D_MODEL + d;
      short8 a = *(const short8*)(ob + base);
      short8 b = *(const short8*)(ob + HALF + base);
#pragma unroll
      for (int j = 0; j < 8; ++j)
        r[j] += g * (bf2f((unsigned short)a[j]) + bf2f((unsigned short)b[j]));
    }
  }
  float4* o = (float4*)(out + (size_t)t * D_MODEL + d);
  o[0] = make_float4(r[0], r[1], r[2], r[3]);
  o[1] = make_float4(r[4], r[5], r[6], r[7]);
}

extern "C" void kernel_launch(void* const* d_in, const int* in_sizes, int n_in,
                              void* d_out, int out_size, void* d_ws, size_t ws_size,
                              hipStream_t stream) {
  const float* x     = (const float*)d_in[0];
  const float* noise = (const float*)d_in[1];
  const float* rw    = (const float*)d_in[2];
  const float* rb    = (const float*)d_in[3];
  const float* nw    = (const float*)d_in[4];
  const float* nb    = (const float*)d_in[5];
  const float* w1    = (const float*)d_in[6];
  const float* w3    = (const float*)d_in[7];
  const float* w2    = (const float*)d_in[8];
  float* out = (float*)d_out;

  char* ws = (char*)d_ws;
  size_t off = 0;
  auto alloc = [&](size_t bytes) -> void* {
    void* p = ws + off;
    off += (bytes + 255) & ~(size_t)255;
    return p;
  };
  const size_t WELEM = (size_t)8 * HIDDEN * D_MODEL;   // 23,068,672
  unsigned short* wb1 = (unsigned short*)alloc(WELEM * 2);
  unsigned short* wb3 = (unsigned short*)alloc(WELEM * 2);
  unsigned short* wb2 = (unsigned short*)alloc(WELEM * 2);
  unsigned short* xb  = (unsigned short*)alloc((size_t)8 * CAP * D_MODEL * 2);
  unsigned short* h   = (unsigned short*)alloc((size_t)8 * CAP * HIDDEN * 2);
  unsigned short* ob  = (unsigned short*)alloc((size_t)2 * 8 * CAP * D_MODEL * 2); // bf16 partials
  int*   topi  = (int*)alloc(N_TOK * 2 * 4);
  float* gall  = (float*)alloc(N_TOK * 2 * 4);
  int*   slot  = (int*)alloc(N_TOK * 2 * 4);
  int*   tokl  = (int*)alloc(8 * CAP * 4);
  (void)ws_size; (void)in_sizes; (void)n_in; (void)out_size;

  // cvt3: nontemporal, 8 floats/thread. WELEM/8/256 = 11264 blocks per array.
  cvt3_kernel<<<dim3((unsigned)(WELEM / 8 / 256), 3), 256, 0, stream>>>(
      w1, w3, w2, wb1, wb3, wb2);

  router_kernel<<<N_TOK / 4, 256, 0, stream>>>(x, noise, rw, rb, nw, nb, topi, gall, slot);
  scan_kernel<<<8, 1024, 0, stream>>>(topi, slot, tokl);
  gather_kernel<<<8 * CAP, 256, 0, stream>>>(x, tokl, xb);

  // FUSE GEMM12 + silu: h = silu(xb@w1^T) * (xb@w3^T), bf16. 704 wgs, bm-fastest decode.
  gemm_moe<HIDDEN, D_MODEL, 2, 1><<<dim3(704), 512, 0, stream>>>(xb, wb1, wb3, (void*)h);

  // PART GEMM3: ob[sk] = bf16(h @ w2^T partials). BN=256, split-K2: 256 wgs.
  gemm_moe<D_MODEL, HIDDEN, 2, 2><<<dim3(256), 512, 0, stream>>>(
      h, wb2, wb2 + (size_t)128 * HIDDEN, (void*)ob);

  // combine bf16 partials with gates; plain stores
  combine_kernel<<<N_TOK, 128, 0, stream>>>(ob, topi, gall, slot, out);
}